// Round 12
// baseline (752.726 us; speedup 1.0000x reference)
//
#include <hip/hip_runtime.h>
#include <hip/hip_bf16.h>
#include <math.h>

#define NEG_SLOPE 0.2f
#define CHUNK 2048      // edges per k_bin block
#define NPB2 128        // nodes per coarse bucket
#define SCAP 5120       // k_sort LDS capacity (bucket mean ~4092, sd ~64)

__device__ __forceinline__ unsigned f2bf(float f) {
  unsigned u = __float_as_uint(f);
  return (u + 0x7fffu + ((u >> 16) & 1u)) >> 16;  // RNE
}

// ---------------------------------------------------------------------------
// K1: h = x @ W + b_W (registers), emit:
//   hb [N][64] uint : {bf16 h(head0,d) lo | bf16 h(head1,d) hi}
//   ai [N][2], aj [N][2] : per-node attention scalars
// ---------------------------------------------------------------------------
__global__ __launch_bounds__(128) void k1_gemm(
    const float* __restrict__ x, const float* __restrict__ W,
    const float* __restrict__ bW, const float* __restrict__ att,
    unsigned int* __restrict__ hb, float* __restrict__ ai,
    float* __restrict__ aj, int Nn) {
  __shared__ float Ws[64 * 128];
  __shared__ float xs[64];
  __shared__ float bs[128];
  __shared__ float atts[256];
  __shared__ float hsh[128];
  int t = threadIdx.x;
  for (int i = t; i < 64 * 128; i += 128) Ws[i] = W[i];
  bs[t] = bW[t];
  atts[t] = att[t];
  atts[128 + t] = att[128 + t];
  __syncthreads();
  int head = t >> 6;
  int lane = t & 63;
  for (int row = blockIdx.x; row < Nn; row += gridDim.x) {
    if (t < 64) xs[t] = x[(size_t)row * 64 + t];
    __syncthreads();
    float acc = bs[t];
#pragma unroll
    for (int k = 0; k < 64; ++k) acc += xs[k] * Ws[k * 128 + t];
    hsh[t] = acc;
    float ti = atts[head * 128 + lane] * acc;
    float tj = atts[head * 128 + 64 + lane] * acc;
#pragma unroll
    for (int off = 32; off > 0; off >>= 1) {
      ti += __shfl_down(ti, off, 64);
      tj += __shfl_down(tj, off, 64);
    }
    if (lane == 0) { ai[row * 2 + head] = ti; aj[row * 2 + head] = tj; }
    __syncthreads();
    if (t < 64)
      hb[(size_t)row * 64 + t] = f2bf(hsh[t]) | (f2bf(hsh[64 + t]) << 16);
  }
}

// ---------------------------------------------------------------------------
// K_sden: dedicated high-occupancy softmax-denominator pass.
// Grid-stride; per edge: lg -> leaky -> exp -> atomicAdd sden[src*2+h].
// ---------------------------------------------------------------------------
__global__ __launch_bounds__(256) void k_sden(
    const int* __restrict__ ei, const int* __restrict__ eattr,
    const float* __restrict__ att, const float* __restrict__ bemb,
    const float2* __restrict__ ai2, const float2* __restrict__ aj2,
    float* __restrict__ sden, int Ee) {
  __shared__ float tbl[30];
  int t = threadIdx.x;
  if (t < 30) {
    int f = t / 10, rem = t % 10, c = rem >> 1, hh = rem & 1;
    float sacc = 0.f;
    for (int d = 0; d < 64; ++d)
      sacc += att[hh * 128 + 64 + d] * bemb[(f * 5 + c) * 128 + hh * 64 + d];
    tbl[t] = sacc;
  }
  __syncthreads();
  int stride = gridDim.x * 256;
  for (int e = blockIdx.x * 256 + t; e < Ee; e += stride) {
    int dst = __builtin_nontemporal_load(&ei[Ee + e]);
    int src = __builtin_nontemporal_load(&ei[e]);
    int a0 = __builtin_nontemporal_load(&eattr[e * 3]);
    int a1 = __builtin_nontemporal_load(&eattr[e * 3 + 1]);
    int a2 = __builtin_nontemporal_load(&eattr[e * 3 + 2]);
    float2 aiv = ai2[dst];
    float2 ajv = aj2[src];
    float lg0 = aiv.x + ajv.x + tbl[a0 * 2] + tbl[10 + a1 * 2] + tbl[20 + a2 * 2];
    float lg1 = aiv.y + ajv.y + tbl[a0 * 2 + 1] + tbl[10 + a1 * 2 + 1] +
                tbl[20 + a2 * 2 + 1];
    lg0 = lg0 >= 0.f ? lg0 : NEG_SLOPE * lg0;
    lg1 = lg1 >= 0.f ? lg1 : NEG_SLOPE * lg1;
    atomicAdd(&sden[src * 2], __expf(lg0));
    atomicAdd(&sden[src * 2 + 1], __expf(lg1));
  }
}

// ---------------------------------------------------------------------------
// K_bin: PURE binning (no float math). Each block owns a 2048-edge chunk and
// a private contiguous window of rec; multi-split by coarse bucket cb=dst>>7
// staged in LDS, flushed sequentially. Edges held in registers (one pass).
// Record: {src:16 | (a0+5a1+25a2)<<16 | (dst&127)<<23}.
// ---------------------------------------------------------------------------
__global__ __launch_bounds__(256) void k_bin(
    const int* __restrict__ ei, const int* __restrict__ eattr,
    unsigned int* __restrict__ rec, int* __restrict__ cnt_tbl,
    int* __restrict__ base_tbl, int Ee, int NCB) {
  __shared__ unsigned sbuf[CHUNK];  // 8 KB staging
  __shared__ int hist[512];
  __shared__ int cur[512];
  int t = threadIdx.x;
  for (int i = t; i < NCB; i += 256) hist[i] = 0;
  __syncthreads();
  int start = blockIdx.x * CHUNK;
  int end = min(start + CHUNK, Ee);
  int cnt = end - start;
  int cbv[CHUNK / 256];
  unsigned pkv[CHUNK / 256];
  int nk = 0;
  for (int e = start + t; e < end; e += 256, ++nk) {
    int dst = __builtin_nontemporal_load(&ei[Ee + e]);
    int src = __builtin_nontemporal_load(&ei[e]);
    int a0 = __builtin_nontemporal_load(&eattr[e * 3]);
    int a1 = __builtin_nontemporal_load(&eattr[e * 3 + 1]);
    int a2 = __builtin_nontemporal_load(&eattr[e * 3 + 2]);
    cbv[nk] = dst >> 7;
    pkv[nk] = (unsigned)src | ((unsigned)(a0 + 5 * a1 + 25 * a2) << 16) |
              ((unsigned)(dst & 127) << 23);
    atomicAdd(&hist[dst >> 7], 1);
  }
  __syncthreads();
  if (t == 0) {
    int s = 0;
    for (int i = 0; i < NCB; ++i) { cur[i] = s; s += hist[i]; }
  }
  __syncthreads();
  for (int i = t; i < NCB; i += 256) {
    cnt_tbl[blockIdx.x * NCB + i] = hist[i];
    base_tbl[blockIdx.x * NCB + i] = cur[i];
  }
  __syncthreads();
  for (int k = 0; k < nk; ++k) {
    int pos = atomicAdd(&cur[cbv[k]], 1);
    sbuf[pos] = pkv[k];
  }
  __syncthreads();
  for (int i = t; i < cnt; i += 256)
    __builtin_nontemporal_store(sbuf[i], &rec[start + i]);
}

// ---------------------------------------------------------------------------
// K_segoff: per-(cb,block) staging destinations + coarse-bucket bases.
// One 512-thread block; thread t owns coarse bucket t (t < NCB).
// ---------------------------------------------------------------------------
__global__ __launch_bounds__(512) void k_segoff(
    const int* __restrict__ cnt_tbl, int* __restrict__ segdst,
    int* __restrict__ coarse_base, int NCB, int NBLK, int Ee) {
  __shared__ int s[512];
  int t = threadIdx.x;
  int run = 0;
  if (t < NCB) {
    for (int blk = 0; blk < NBLK; ++blk) {
      segdst[t * NBLK + blk] = run;
      run += cnt_tbl[blk * NCB + t];
    }
  }
  s[t] = run;
  __syncthreads();
#pragma unroll
  for (int o = 1; o < 512; o <<= 1) {
    int xv = (t >= o) ? s[t - o] : 0;
    __syncthreads();
    s[t] += xv;
    __syncthreads();
  }
  if (t < NCB) coarse_base[t] = s[t] - run;  // exclusive
  if (t == 0) coarse_base[NCB] = Ee;
}

// ---------------------------------------------------------------------------
// K_sort: one block per coarse bucket (128 nodes, ~4096 edges, 40 KB LDS ->
// ~3 blocks/CU). Per-THREAD segment staging, LDS counting sort by node-local
// id, then a 4-deep unrolled sequential output phase computing final alpha
// (batched random aj/sden reads) with fully coalesced eix2/alpha2 writes.
// ---------------------------------------------------------------------------
__global__ __launch_bounds__(256) void k_sort(
    const unsigned int* __restrict__ rec, const int* __restrict__ cnt_tbl,
    const int* __restrict__ base_tbl, const int* __restrict__ segdst,
    const int* __restrict__ coarse_base, const float2* __restrict__ ai2,
    const float2* __restrict__ aj2, const float2* __restrict__ sd2,
    const float* __restrict__ att, const float* __restrict__ bemb,
    unsigned int* __restrict__ eix2, float2* __restrict__ alpha2,
    int* __restrict__ off, int Nn, int NCB, int NBLK, int Ee) {
  __shared__ unsigned ubuf[SCAP];   // 20 KB
  __shared__ unsigned ubuf2[SCAP];  // 20 KB
  __shared__ int hist[NPB2], basex[NPB2], curx[NPB2];
  __shared__ float tbl[30];
  __shared__ float2 ais[NPB2];
  int t = threadIdx.x;
  int cb = blockIdx.x;
  if (t < 30) {
    int f = t / 10, rem = t % 10, c = rem >> 1, hh = rem & 1;
    float sacc = 0.f;
    for (int d = 0; d < 64; ++d)
      sacc += att[hh * 128 + 64 + d] * bemb[(f * 5 + c) * 128 + hh * 64 + d];
    tbl[t] = sacc;
  }
  int node0 = cb << 7;
  if (t < NPB2) {
    hist[t] = 0;
    if (node0 + t < Nn) ais[t] = ai2[node0 + t];
  }
  int gbase = coarse_base[cb];
  int total = coarse_base[cb + 1] - gbase;
  __syncthreads();
  bool fits = (total <= SCAP);

  if (fits) {
    // stage: thread t copies segments blk = t, t+256, ...
    for (int blk = t; blk < NBLK; blk += 256) {
      int len = cnt_tbl[blk * NCB + cb];
      if (!len) continue;
      int sp = blk * CHUNK + base_tbl[blk * NCB + cb];
      int dp = segdst[cb * NBLK + blk];
      for (int j = 0; j < len; ++j) ubuf[dp + j] = rec[sp + j];
    }
    __syncthreads();
    for (int i = t; i < total; i += 256)
      atomicAdd(&hist[(ubuf[i] >> 23) & 127], 1);
    __syncthreads();
    if (t == 0) {
      int s = 0;
      for (int i = 0; i < NPB2; ++i) { basex[i] = s; s += hist[i]; }
    }
    __syncthreads();
    if (t < NPB2) {
      curx[t] = basex[t];
      if (node0 + t < Nn) off[node0 + t] = gbase + basex[t];
    }
    if (cb == 0 && t == 0) off[Nn] = Ee;
    __syncthreads();
    for (int i = t; i < total; i += 256) {
      unsigned u = ubuf[i];
      int pos = atomicAdd(&curx[(u >> 23) & 127], 1);
      ubuf2[pos] = u;
    }
    __syncthreads();

#define OUT_BODY(I, U, AJV, SDV)                                               \
    {                                                                          \
      int src = (U) & 0xFFFF;                                                  \
      int c012 = ((U) >> 16) & 127;                                            \
      int dl = ((U) >> 23) & 127;                                              \
      int a0 = c012 % 5, a1 = (c012 / 5) % 5, a2 = c012 / 25;                  \
      float2 aiv = ais[dl];                                                    \
      float lg0 = aiv.x + AJV.x + tbl[a0 * 2] + tbl[10 + a1 * 2] +             \
                  tbl[20 + a2 * 2];                                            \
      float lg1 = aiv.y + AJV.y + tbl[a0 * 2 + 1] + tbl[10 + a1 * 2 + 1] +     \
                  tbl[20 + a2 * 2 + 1];                                        \
      lg0 = lg0 >= 0.f ? lg0 : NEG_SLOPE * lg0;                                \
      lg1 = lg1 >= 0.f ? lg1 : NEG_SLOPE * lg1;                                \
      eix2[gbase + (I)] = (unsigned)src | ((unsigned)a0 << 16) |               \
                          ((unsigned)a1 << 19) | ((unsigned)a2 << 22);         \
      alpha2[gbase + (I)] = make_float2(__expf(lg0) / (SDV.x + 1e-16f),        \
                                        __expf(lg1) / (SDV.y + 1e-16f));       \
    }

    int i = t;
    for (; i + 3 * 256 < total; i += 4 * 256) {
      unsigned u[4];
      float2 ajv[4], sdv[4];
#pragma unroll
      for (int k = 0; k < 4; ++k) u[k] = ubuf2[i + k * 256];
#pragma unroll
      for (int k = 0; k < 4; ++k) ajv[k] = aj2[u[k] & 0xFFFF];
#pragma unroll
      for (int k = 0; k < 4; ++k) sdv[k] = sd2[u[k] & 0xFFFF];
#pragma unroll
      for (int k = 0; k < 4; ++k) OUT_BODY(i + k * 256, u[k], ajv[k], sdv[k])
    }
    for (; i < total; i += 256) {
      unsigned u = ubuf2[i];
      float2 ajv = aj2[u & 0xFFFF];
      float2 sdv = sd2[u & 0xFFFF];
      OUT_BODY(i, u, ajv, sdv)
    }
#undef OUT_BODY
  } else {
    // fallback (statistically unreachable): global-read path
    for (int blk = t; blk < NBLK; blk += 256) {
      int len = cnt_tbl[blk * NCB + cb];
      int sp = blk * CHUNK + base_tbl[blk * NCB + cb];
      for (int j = 0; j < len; ++j)
        atomicAdd(&hist[(rec[sp + j] >> 23) & 127], 1);
    }
    __syncthreads();
    if (t == 0) {
      int s = 0;
      for (int i = 0; i < NPB2; ++i) { basex[i] = s; s += hist[i]; }
    }
    __syncthreads();
    if (t < NPB2) {
      curx[t] = basex[t];
      if (node0 + t < Nn) off[node0 + t] = gbase + basex[t];
    }
    if (cb == 0 && t == 0) off[Nn] = Ee;
    __syncthreads();
    for (int blk = t; blk < NBLK; blk += 256) {
      int len = cnt_tbl[blk * NCB + cb];
      int sp = blk * CHUNK + base_tbl[blk * NCB + cb];
      for (int j = 0; j < len; ++j) {
        unsigned u = rec[sp + j];
        int src = u & 0xFFFF;
        int c012 = (u >> 16) & 127;
        int dl = (u >> 23) & 127;
        int a0 = c012 % 5, a1 = (c012 / 5) % 5, a2 = c012 / 25;
        float2 aiv = ais[dl];
        float2 ajv = aj2[src];
        float2 sdv = sd2[src];
        float lg0 = aiv.x + ajv.x + tbl[a0 * 2] + tbl[10 + a1 * 2] + tbl[20 + a2 * 2];
        float lg1 = aiv.y + ajv.y + tbl[a0 * 2 + 1] + tbl[10 + a1 * 2 + 1] +
                    tbl[20 + a2 * 2 + 1];
        lg0 = lg0 >= 0.f ? lg0 : NEG_SLOPE * lg0;
        lg1 = lg1 >= 0.f ? lg1 : NEG_SLOPE * lg1;
        int pos = gbase + atomicAdd(&curx[dl], 1);
        eix2[pos] = (unsigned)src | ((unsigned)a0 << 16) | ((unsigned)a1 << 19) |
                    ((unsigned)a2 << 22);
        alpha2[pos] = make_float2(__expf(lg0) / (sdv.x + 1e-16f),
                                  __expf(lg1) / (sdv.y + 1e-16f));
      }
    }
  }
}

// ---------------------------------------------------------------------------
// K_gather: one wave per dst node, lane = d. Per edge: sequential rec+alpha
// reads, one coalesced hb gather, 2 FMA + predicated w-update. Edge-emb term
// hoisted: lanes 0..29 accumulate w[f,c,h]; epilogue adds 15-term weighted
// bemb sum.
// ---------------------------------------------------------------------------
__global__ __launch_bounds__(256) void k_gather(
    const unsigned int* __restrict__ eix, const float2* __restrict__ alpha2,
    const int* __restrict__ off, const unsigned int* __restrict__ hb,
    const float* __restrict__ bemb, const float* __restrict__ bias,
    float* __restrict__ out, int Nn) {
  __shared__ float bembs[15 * 128];  // [f*5+c][128]
  __shared__ float wsm[4][32];
  int t = threadIdx.x;
  for (int i = t; i < 15 * 128; i += 256) bembs[i] = bemb[i];
  __syncthreads();
  int wave = t >> 6, lane = t & 63;
  int n = blockIdx.x * 4 + wave;
  if (n >= Nn) return;
  int p0 = off[n], p1 = off[n + 1];
  int myf = lane / 10;
  int myc = (lane % 10) >> 1;
  bool myh = (lane & 1) != 0;
  bool active = lane < 30;
  float w = 0.f;
  float acc0 = 0.f, acc1 = 0.f;

#define EDGE_BODY(U, HV, AL)                                                   \
  {                                                                            \
    acc0 += AL.x * __uint_as_float(HV << 16);                                  \
    acc1 += AL.y * __uint_as_float(HV & 0xffff0000u);                          \
    int a0 = (U >> 16) & 7, a1 = (U >> 19) & 7, a2 = (U >> 22) & 7;            \
    int sel = myf == 0 ? a0 : (myf == 1 ? a1 : a2);                            \
    w += (active && myc == sel) ? (myh ? AL.y : AL.x) : 0.f;                   \
  }

  int p = p0;
  for (; p + 8 <= p1; p += 8) {
    unsigned u[8], hv[8];
    float2 al[8];
#pragma unroll
    for (int k = 0; k < 8; ++k) u[k] = eix[p + k];
#pragma unroll
    for (int k = 0; k < 8; ++k) al[k] = alpha2[p + k];
#pragma unroll
    for (int k = 0; k < 8; ++k)
      hv[k] = hb[(size_t)(u[k] & 0xFFFF) * 64 + lane];
#pragma unroll
    for (int k = 0; k < 8; ++k) EDGE_BODY(u[k], hv[k], al[k])
  }
  for (; p < p1; ++p) {
    unsigned u0 = eix[p];
    float2 al0 = alpha2[p];
    unsigned hv0 = hb[(size_t)(u0 & 0xFFFF) * 64 + lane];
    EDGE_BODY(u0, hv0, al0)
  }
#undef EDGE_BODY

  if (active) wsm[wave][lane] = w;  // same-wave LDS ops are in-order
#pragma unroll
  for (int k = 0; k < 15; ++k) {
    acc0 += wsm[wave][k * 2] * bembs[k * 128 + lane];
    acc1 += wsm[wave][k * 2 + 1] * bembs[k * 128 + 64 + lane];
  }
  out[(size_t)n * 64 + lane] = 0.5f * (acc0 + acc1) + bias[lane];
}

extern "C" void kernel_launch(void* const* d_in, const int* in_sizes, int n_in,
                              void* d_out, int out_size, void* d_ws, size_t ws_size,
                              hipStream_t stream) {
  const float* x    = (const float*)d_in[0];
  const int*   ei   = (const int*)d_in[1];
  const int*   eatt = (const int*)d_in[2];
  const float* W    = (const float*)d_in[3];
  const float* bW   = (const float*)d_in[4];
  const float* att  = (const float*)d_in[5];
  const float* bias = (const float*)d_in[6];
  const float* bemb = (const float*)d_in[7];
  int Nn = in_sizes[0] / 64;
  int Ee = in_sizes[1] / 2;
  int NCB = (Nn + NPB2 - 1) / NPB2;            // 391 coarse buckets (128 nodes)
  int NBLK = (Ee + CHUNK - 1) / CHUNK;         // 782 bin blocks

  char* ws = (char*)d_ws;
  ws = (char*)(((uintptr_t)ws + 15) & ~(uintptr_t)15);
  float* aj = (float*)ws;                 ws += (size_t)Nn * 2 * 4;
  float* sden = (float*)ws;               ws += (size_t)Nn * 2 * 4;
  float* ai = (float*)ws;                 ws += (size_t)Nn * 2 * 4;
  unsigned int* hb = (unsigned int*)ws;   ws += (size_t)Nn * 64 * 4;
  unsigned int* rec = (unsigned int*)ws;  ws += (size_t)NBLK * CHUNK * 4;
  unsigned int* eix2 = (unsigned int*)ws; ws += (size_t)Ee * 4;
  float2* alpha2 = (float2*)ws;           ws += (size_t)Ee * 8;
  int* off = (int*)ws;                    ws += (size_t)(Nn + 1) * 4;
  int* cnt_tbl = (int*)ws;                ws += (size_t)NBLK * NCB * 4;
  int* base_tbl = (int*)ws;               ws += (size_t)NBLK * NCB * 4;
  int* segdst = (int*)ws;                 ws += (size_t)NCB * NBLK * 4;
  int* coarse_base = (int*)ws;            ws += (size_t)(NCB + 1) * 4;

  hipMemsetAsync(sden, 0, (size_t)Nn * 2 * 4, stream);

  k1_gemm<<<1024, 128, 0, stream>>>(x, W, bW, att, hb, ai, aj, Nn);
  k_sden<<<1024, 256, 0, stream>>>(ei, eatt, att, bemb, (const float2*)ai,
                                   (const float2*)aj, sden, Ee);
  k_bin<<<NBLK, 256, 0, stream>>>(ei, eatt, rec, cnt_tbl, base_tbl, Ee, NCB);
  k_segoff<<<1, 512, 0, stream>>>(cnt_tbl, segdst, coarse_base, NCB, NBLK, Ee);
  k_sort<<<NCB, 256, 0, stream>>>(rec, cnt_tbl, base_tbl, segdst, coarse_base,
                                  (const float2*)ai, (const float2*)aj,
                                  (const float2*)sden, att, bemb, eix2, alpha2,
                                  off, Nn, NCB, NBLK, Ee);
  k_gather<<<(Nn + 3) / 4, 256, 0, stream>>>(eix2, alpha2, off, hb, bemb, bias,
                                             (float*)d_out, Nn);
}

// Round 13
// 462.256 us; speedup vs baseline: 1.6284x; 1.6284x over previous
//
#include <hip/hip_runtime.h>
#include <hip/hip_bf16.h>
#include <math.h>

#define NEG_SLOPE 0.2f
#define CHUNK 2048      // edges per k_bin block
#define NPB2 128        // nodes per coarse bucket
#define SCAP 5120       // k_sort LDS capacity (bucket mean ~4092, sd ~64)

__device__ __forceinline__ unsigned f2bf(float f) {
  unsigned u = __float_as_uint(f);
  return (u + 0x7fffu + ((u >> 16) & 1u)) >> 16;  // RNE
}

// ---------------------------------------------------------------------------
// K1: h = x @ W + b_W (registers), emit:
//   hb [N][64] uint : {bf16 h(head0,d) lo | bf16 h(head1,d) hi}
//   ai [N][2], aj [N][2] : per-node attention scalars
// ---------------------------------------------------------------------------
__global__ __launch_bounds__(128) void k1_gemm(
    const float* __restrict__ x, const float* __restrict__ W,
    const float* __restrict__ bW, const float* __restrict__ att,
    unsigned int* __restrict__ hb, float* __restrict__ ai,
    float* __restrict__ aj, int Nn) {
  __shared__ float Ws[64 * 128];
  __shared__ float xs[64];
  __shared__ float bs[128];
  __shared__ float atts[256];
  __shared__ float hsh[128];
  int t = threadIdx.x;
  for (int i = t; i < 64 * 128; i += 128) Ws[i] = W[i];
  bs[t] = bW[t];
  atts[t] = att[t];
  atts[128 + t] = att[128 + t];
  __syncthreads();
  int head = t >> 6;
  int lane = t & 63;
  for (int row = blockIdx.x; row < Nn; row += gridDim.x) {
    if (t < 64) xs[t] = x[(size_t)row * 64 + t];
    __syncthreads();
    float acc = bs[t];
#pragma unroll
    for (int k = 0; k < 64; ++k) acc += xs[k] * Ws[k * 128 + t];
    hsh[t] = acc;
    float ti = atts[head * 128 + lane] * acc;
    float tj = atts[head * 128 + 64 + lane] * acc;
#pragma unroll
    for (int off = 32; off > 0; off >>= 1) {
      ti += __shfl_down(ti, off, 64);
      tj += __shfl_down(tj, off, 64);
    }
    if (lane == 0) { ai[row * 2 + head] = ti; aj[row * 2 + head] = tj; }
    __syncthreads();
    if (t < 64)
      hb[(size_t)row * 64 + t] = f2bf(hsh[t]) | (f2bf(hsh[64 + t]) << 16);
  }
}

// ---------------------------------------------------------------------------
// K_sden: dedicated high-occupancy softmax-denominator pass.
// Grid-stride; per edge: lg -> leaky -> exp -> atomicAdd sden[src*2+h].
// ---------------------------------------------------------------------------
__global__ __launch_bounds__(256) void k_sden(
    const int* __restrict__ ei, const int* __restrict__ eattr,
    const float* __restrict__ att, const float* __restrict__ bemb,
    const float2* __restrict__ ai2, const float2* __restrict__ aj2,
    float* __restrict__ sden, int Ee) {
  __shared__ float tbl[30];
  int t = threadIdx.x;
  if (t < 30) {
    int f = t / 10, rem = t % 10, c = rem >> 1, hh = rem & 1;
    float sacc = 0.f;
    for (int d = 0; d < 64; ++d)
      sacc += att[hh * 128 + 64 + d] * bemb[(f * 5 + c) * 128 + hh * 64 + d];
    tbl[t] = sacc;
  }
  __syncthreads();
  int stride = gridDim.x * 256;
  for (int e = blockIdx.x * 256 + t; e < Ee; e += stride) {
    int dst = __builtin_nontemporal_load(&ei[Ee + e]);
    int src = __builtin_nontemporal_load(&ei[e]);
    int a0 = __builtin_nontemporal_load(&eattr[e * 3]);
    int a1 = __builtin_nontemporal_load(&eattr[e * 3 + 1]);
    int a2 = __builtin_nontemporal_load(&eattr[e * 3 + 2]);
    float2 aiv = ai2[dst];
    float2 ajv = aj2[src];
    float lg0 = aiv.x + ajv.x + tbl[a0 * 2] + tbl[10 + a1 * 2] + tbl[20 + a2 * 2];
    float lg1 = aiv.y + ajv.y + tbl[a0 * 2 + 1] + tbl[10 + a1 * 2 + 1] +
                tbl[20 + a2 * 2 + 1];
    lg0 = lg0 >= 0.f ? lg0 : NEG_SLOPE * lg0;
    lg1 = lg1 >= 0.f ? lg1 : NEG_SLOPE * lg1;
    atomicAdd(&sden[src * 2], __expf(lg0));
    atomicAdd(&sden[src * 2 + 1], __expf(lg1));
  }
}

// ---------------------------------------------------------------------------
// K_bin: PURE binning (no float math). Each block owns a 2048-edge chunk and
// a private contiguous window of rec; multi-split by coarse bucket cb=dst>>7
// staged in LDS, flushed sequentially. Edges held in registers (one pass).
// Record: {src:16 | (a0+5a1+25a2)<<16 | (dst&127)<<23}.
// ---------------------------------------------------------------------------
__global__ __launch_bounds__(256) void k_bin(
    const int* __restrict__ ei, const int* __restrict__ eattr,
    unsigned int* __restrict__ rec, int* __restrict__ cnt_tbl,
    int* __restrict__ base_tbl, int Ee, int NCB) {
  __shared__ unsigned sbuf[CHUNK];  // 8 KB staging
  __shared__ int hist[512];
  __shared__ int cur[512];
  int t = threadIdx.x;
  for (int i = t; i < NCB; i += 256) hist[i] = 0;
  __syncthreads();
  int start = blockIdx.x * CHUNK;
  int end = min(start + CHUNK, Ee);
  int cnt = end - start;
  int cbv[CHUNK / 256];
  unsigned pkv[CHUNK / 256];
  int nk = 0;
  for (int e = start + t; e < end; e += 256, ++nk) {
    int dst = __builtin_nontemporal_load(&ei[Ee + e]);
    int src = __builtin_nontemporal_load(&ei[e]);
    int a0 = __builtin_nontemporal_load(&eattr[e * 3]);
    int a1 = __builtin_nontemporal_load(&eattr[e * 3 + 1]);
    int a2 = __builtin_nontemporal_load(&eattr[e * 3 + 2]);
    cbv[nk] = dst >> 7;
    pkv[nk] = (unsigned)src | ((unsigned)(a0 + 5 * a1 + 25 * a2) << 16) |
              ((unsigned)(dst & 127) << 23);
    atomicAdd(&hist[dst >> 7], 1);
  }
  __syncthreads();
  if (t == 0) {
    int s = 0;
    for (int i = 0; i < NCB; ++i) { cur[i] = s; s += hist[i]; }
  }
  __syncthreads();
  for (int i = t; i < NCB; i += 256) {
    cnt_tbl[blockIdx.x * NCB + i] = hist[i];
    base_tbl[blockIdx.x * NCB + i] = cur[i];
  }
  __syncthreads();
  for (int k = 0; k < nk; ++k) {
    int pos = atomicAdd(&cur[cbv[k]], 1);
    sbuf[pos] = pkv[k];
  }
  __syncthreads();
  for (int i = t; i < cnt; i += 256)
    __builtin_nontemporal_store(sbuf[i], &rec[start + i]);
}

// ---------------------------------------------------------------------------
// K_segoff_a: PARALLEL per-bucket segment-offset scan. One block per coarse
// bucket cb; 256-thread exclusive scan over the NBLK per-block counts ->
// segdst[cb][blk] (coalesced) + bucket total.
// ---------------------------------------------------------------------------
__global__ __launch_bounds__(256) void k_segoff_a(
    const int* __restrict__ cnt_tbl, int* __restrict__ segdst,
    int* __restrict__ btot, int NCB, int NBLK) {
  __shared__ int s[256];
  int t = threadIdx.x, cb = blockIdx.x;
  int per = (NBLK + 255) / 256;  // 4 at NBLK=782
  int loc[8];
  int sum = 0;
  for (int j = 0; j < per; ++j) {
    int blk = t * per + j;
    int v = (blk < NBLK) ? cnt_tbl[blk * NCB + cb] : 0;
    loc[j] = sum;
    sum += v;
  }
  s[t] = sum;
  __syncthreads();
#pragma unroll
  for (int o = 1; o < 256; o <<= 1) {
    int xv = (t >= o) ? s[t - o] : 0;
    __syncthreads();
    s[t] += xv;
    __syncthreads();
  }
  int excl = s[t] - sum;
  for (int j = 0; j < per; ++j) {
    int blk = t * per + j;
    if (blk < NBLK) segdst[cb * NBLK + blk] = excl + loc[j];
  }
  if (t == 255) btot[cb] = s[255];
}

// ---------------------------------------------------------------------------
// K_segoff_b: tiny single-block exclusive scan over bucket totals.
// ---------------------------------------------------------------------------
__global__ __launch_bounds__(512) void k_segoff_b(
    const int* __restrict__ btot, int* __restrict__ coarse_base, int NCB, int Ee) {
  __shared__ int s[512];
  int t = threadIdx.x;
  int v = (t < NCB) ? btot[t] : 0;
  s[t] = v;
  __syncthreads();
#pragma unroll
  for (int o = 1; o < 512; o <<= 1) {
    int xv = (t >= o) ? s[t - o] : 0;
    __syncthreads();
    s[t] += xv;
    __syncthreads();
  }
  if (t < NCB) coarse_base[t] = s[t] - v;
  if (t == 0) coarse_base[NCB] = Ee;
}

// ---------------------------------------------------------------------------
// K_sort: one block per coarse bucket (128 nodes, ~4096 edges, 40 KB LDS ->
// ~3 blocks/CU). Per-THREAD segment staging, LDS counting sort by node-local
// id, then a 4-deep unrolled sequential output phase computing final alpha
// (batched random aj/sden reads) with fully coalesced eix2/alpha2 writes.
// ---------------------------------------------------------------------------
__global__ __launch_bounds__(256) void k_sort(
    const unsigned int* __restrict__ rec, const int* __restrict__ cnt_tbl,
    const int* __restrict__ base_tbl, const int* __restrict__ segdst,
    const int* __restrict__ coarse_base, const float2* __restrict__ ai2,
    const float2* __restrict__ aj2, const float2* __restrict__ sd2,
    const float* __restrict__ att, const float* __restrict__ bemb,
    unsigned int* __restrict__ eix2, float2* __restrict__ alpha2,
    int* __restrict__ off, int Nn, int NCB, int NBLK, int Ee) {
  __shared__ unsigned ubuf[SCAP];   // 20 KB
  __shared__ unsigned ubuf2[SCAP];  // 20 KB
  __shared__ int hist[NPB2], basex[NPB2], curx[NPB2];
  __shared__ float tbl[30];
  __shared__ float2 ais[NPB2];
  int t = threadIdx.x;
  int cb = blockIdx.x;
  if (t < 30) {
    int f = t / 10, rem = t % 10, c = rem >> 1, hh = rem & 1;
    float sacc = 0.f;
    for (int d = 0; d < 64; ++d)
      sacc += att[hh * 128 + 64 + d] * bemb[(f * 5 + c) * 128 + hh * 64 + d];
    tbl[t] = sacc;
  }
  int node0 = cb << 7;
  if (t < NPB2) {
    hist[t] = 0;
    if (node0 + t < Nn) ais[t] = ai2[node0 + t];
  }
  int gbase = coarse_base[cb];
  int total = coarse_base[cb + 1] - gbase;
  __syncthreads();
  bool fits = (total <= SCAP);

  if (fits) {
    // stage: thread t copies segments blk = t, t+256, ...
    for (int blk = t; blk < NBLK; blk += 256) {
      int len = cnt_tbl[blk * NCB + cb];
      if (!len) continue;
      int sp = blk * CHUNK + base_tbl[blk * NCB + cb];
      int dp = segdst[cb * NBLK + blk];
      for (int j = 0; j < len; ++j) ubuf[dp + j] = rec[sp + j];
    }
    __syncthreads();
    for (int i = t; i < total; i += 256)
      atomicAdd(&hist[(ubuf[i] >> 23) & 127], 1);
    __syncthreads();
    if (t == 0) {
      int s = 0;
      for (int i = 0; i < NPB2; ++i) { basex[i] = s; s += hist[i]; }
    }
    __syncthreads();
    if (t < NPB2) {
      curx[t] = basex[t];
      if (node0 + t < Nn) off[node0 + t] = gbase + basex[t];
    }
    if (cb == 0 && t == 0) off[Nn] = Ee;
    __syncthreads();
    for (int i = t; i < total; i += 256) {
      unsigned u = ubuf[i];
      int pos = atomicAdd(&curx[(u >> 23) & 127], 1);
      ubuf2[pos] = u;
    }
    __syncthreads();

#define OUT_BODY(I, U, AJV, SDV)                                               \
    {                                                                          \
      int src = (U) & 0xFFFF;                                                  \
      int c012 = ((U) >> 16) & 127;                                            \
      int dl = ((U) >> 23) & 127;                                              \
      int a0 = c012 % 5, a1 = (c012 / 5) % 5, a2 = c012 / 25;                  \
      float2 aiv = ais[dl];                                                    \
      float lg0 = aiv.x + AJV.x + tbl[a0 * 2] + tbl[10 + a1 * 2] +             \
                  tbl[20 + a2 * 2];                                            \
      float lg1 = aiv.y + AJV.y + tbl[a0 * 2 + 1] + tbl[10 + a1 * 2 + 1] +     \
                  tbl[20 + a2 * 2 + 1];                                        \
      lg0 = lg0 >= 0.f ? lg0 : NEG_SLOPE * lg0;                                \
      lg1 = lg1 >= 0.f ? lg1 : NEG_SLOPE * lg1;                                \
      eix2[gbase + (I)] = (unsigned)src | ((unsigned)a0 << 16) |               \
                          ((unsigned)a1 << 19) | ((unsigned)a2 << 22);         \
      alpha2[gbase + (I)] = make_float2(__expf(lg0) / (SDV.x + 1e-16f),        \
                                        __expf(lg1) / (SDV.y + 1e-16f));       \
    }

    int i = t;
    for (; i + 3 * 256 < total; i += 4 * 256) {
      unsigned u[4];
      float2 ajv[4], sdv[4];
#pragma unroll
      for (int k = 0; k < 4; ++k) u[k] = ubuf2[i + k * 256];
#pragma unroll
      for (int k = 0; k < 4; ++k) ajv[k] = aj2[u[k] & 0xFFFF];
#pragma unroll
      for (int k = 0; k < 4; ++k) sdv[k] = sd2[u[k] & 0xFFFF];
#pragma unroll
      for (int k = 0; k < 4; ++k) OUT_BODY(i + k * 256, u[k], ajv[k], sdv[k])
    }
    for (; i < total; i += 256) {
      unsigned u = ubuf2[i];
      float2 ajv = aj2[u & 0xFFFF];
      float2 sdv = sd2[u & 0xFFFF];
      OUT_BODY(i, u, ajv, sdv)
    }
#undef OUT_BODY
  } else {
    // fallback (statistically unreachable): global-read path
    for (int blk = t; blk < NBLK; blk += 256) {
      int len = cnt_tbl[blk * NCB + cb];
      int sp = blk * CHUNK + base_tbl[blk * NCB + cb];
      for (int j = 0; j < len; ++j)
        atomicAdd(&hist[(rec[sp + j] >> 23) & 127], 1);
    }
    __syncthreads();
    if (t == 0) {
      int s = 0;
      for (int i = 0; i < NPB2; ++i) { basex[i] = s; s += hist[i]; }
    }
    __syncthreads();
    if (t < NPB2) {
      curx[t] = basex[t];
      if (node0 + t < Nn) off[node0 + t] = gbase + basex[t];
    }
    if (cb == 0 && t == 0) off[Nn] = Ee;
    __syncthreads();
    for (int blk = t; blk < NBLK; blk += 256) {
      int len = cnt_tbl[blk * NCB + cb];
      int sp = blk * CHUNK + base_tbl[blk * NCB + cb];
      for (int j = 0; j < len; ++j) {
        unsigned u = rec[sp + j];
        int src = u & 0xFFFF;
        int c012 = (u >> 16) & 127;
        int dl = (u >> 23) & 127;
        int a0 = c012 % 5, a1 = (c012 / 5) % 5, a2 = c012 / 25;
        float2 aiv = ais[dl];
        float2 ajv = aj2[src];
        float2 sdv = sd2[src];
        float lg0 = aiv.x + ajv.x + tbl[a0 * 2] + tbl[10 + a1 * 2] + tbl[20 + a2 * 2];
        float lg1 = aiv.y + ajv.y + tbl[a0 * 2 + 1] + tbl[10 + a1 * 2 + 1] +
                    tbl[20 + a2 * 2 + 1];
        lg0 = lg0 >= 0.f ? lg0 : NEG_SLOPE * lg0;
        lg1 = lg1 >= 0.f ? lg1 : NEG_SLOPE * lg1;
        int pos = gbase + atomicAdd(&curx[dl], 1);
        eix2[pos] = (unsigned)src | ((unsigned)a0 << 16) | ((unsigned)a1 << 19) |
                    ((unsigned)a2 << 22);
        alpha2[pos] = make_float2(__expf(lg0) / (sdv.x + 1e-16f),
                                  __expf(lg1) / (sdv.y + 1e-16f));
      }
    }
  }
}

// ---------------------------------------------------------------------------
// K_gather: one wave per dst node, lane = d. Per edge: sequential rec+alpha
// reads, one coalesced hb gather, 2 FMA + predicated w-update. Edge-emb term
// hoisted: lanes 0..29 accumulate w[f,c,h]; epilogue adds 15-term weighted
// bemb sum.
// ---------------------------------------------------------------------------
__global__ __launch_bounds__(256) void k_gather(
    const unsigned int* __restrict__ eix, const float2* __restrict__ alpha2,
    const int* __restrict__ off, const unsigned int* __restrict__ hb,
    const float* __restrict__ bemb, const float* __restrict__ bias,
    float* __restrict__ out, int Nn) {
  __shared__ float bembs[15 * 128];  // [f*5+c][128]
  __shared__ float wsm[4][32];
  int t = threadIdx.x;
  for (int i = t; i < 15 * 128; i += 256) bembs[i] = bemb[i];
  __syncthreads();
  int wave = t >> 6, lane = t & 63;
  int n = blockIdx.x * 4 + wave;
  if (n >= Nn) return;
  int p0 = off[n], p1 = off[n + 1];
  int myf = lane / 10;
  int myc = (lane % 10) >> 1;
  bool myh = (lane & 1) != 0;
  bool active = lane < 30;
  float w = 0.f;
  float acc0 = 0.f, acc1 = 0.f;

#define EDGE_BODY(U, HV, AL)                                                   \
  {                                                                            \
    acc0 += AL.x * __uint_as_float(HV << 16);                                  \
    acc1 += AL.y * __uint_as_float(HV & 0xffff0000u);                          \
    int a0 = (U >> 16) & 7, a1 = (U >> 19) & 7, a2 = (U >> 22) & 7;            \
    int sel = myf == 0 ? a0 : (myf == 1 ? a1 : a2);                            \
    w += (active && myc == sel) ? (myh ? AL.y : AL.x) : 0.f;                   \
  }

  int p = p0;
  for (; p + 8 <= p1; p += 8) {
    unsigned u[8], hv[8];
    float2 al[8];
#pragma unroll
    for (int k = 0; k < 8; ++k) u[k] = eix[p + k];
#pragma unroll
    for (int k = 0; k < 8; ++k) al[k] = alpha2[p + k];
#pragma unroll
    for (int k = 0; k < 8; ++k)
      hv[k] = hb[(size_t)(u[k] & 0xFFFF) * 64 + lane];
#pragma unroll
    for (int k = 0; k < 8; ++k) EDGE_BODY(u[k], hv[k], al[k])
  }
  for (; p < p1; ++p) {
    unsigned u0 = eix[p];
    float2 al0 = alpha2[p];
    unsigned hv0 = hb[(size_t)(u0 & 0xFFFF) * 64 + lane];
    EDGE_BODY(u0, hv0, al0)
  }
#undef EDGE_BODY

  if (active) wsm[wave][lane] = w;  // same-wave LDS ops are in-order
#pragma unroll
  for (int k = 0; k < 15; ++k) {
    acc0 += wsm[wave][k * 2] * bembs[k * 128 + lane];
    acc1 += wsm[wave][k * 2 + 1] * bembs[k * 128 + 64 + lane];
  }
  out[(size_t)n * 64 + lane] = 0.5f * (acc0 + acc1) + bias[lane];
}

extern "C" void kernel_launch(void* const* d_in, const int* in_sizes, int n_in,
                              void* d_out, int out_size, void* d_ws, size_t ws_size,
                              hipStream_t stream) {
  const float* x    = (const float*)d_in[0];
  const int*   ei   = (const int*)d_in[1];
  const int*   eatt = (const int*)d_in[2];
  const float* W    = (const float*)d_in[3];
  const float* bW   = (const float*)d_in[4];
  const float* att  = (const float*)d_in[5];
  const float* bias = (const float*)d_in[6];
  const float* bemb = (const float*)d_in[7];
  int Nn = in_sizes[0] / 64;
  int Ee = in_sizes[1] / 2;
  int NCB = (Nn + NPB2 - 1) / NPB2;            // 391 coarse buckets (128 nodes)
  int NBLK = (Ee + CHUNK - 1) / CHUNK;         // 782 bin blocks

  char* ws = (char*)d_ws;
  ws = (char*)(((uintptr_t)ws + 15) & ~(uintptr_t)15);
  float* aj = (float*)ws;                 ws += (size_t)Nn * 2 * 4;
  float* sden = (float*)ws;               ws += (size_t)Nn * 2 * 4;
  float* ai = (float*)ws;                 ws += (size_t)Nn * 2 * 4;
  unsigned int* hb = (unsigned int*)ws;   ws += (size_t)Nn * 64 * 4;
  unsigned int* rec = (unsigned int*)ws;  ws += (size_t)NBLK * CHUNK * 4;
  unsigned int* eix2 = (unsigned int*)ws; ws += (size_t)Ee * 4;
  float2* alpha2 = (float2*)ws;           ws += (size_t)Ee * 8;
  int* off = (int*)ws;                    ws += (size_t)(Nn + 1) * 4;
  int* cnt_tbl = (int*)ws;                ws += (size_t)NBLK * NCB * 4;
  int* base_tbl = (int*)ws;               ws += (size_t)NBLK * NCB * 4;
  int* segdst = (int*)ws;                 ws += (size_t)NCB * NBLK * 4;
  int* coarse_base = (int*)ws;            ws += (size_t)(NCB + 1) * 4;
  int* btot = (int*)ws;                   ws += (size_t)NCB * 4;

  hipMemsetAsync(sden, 0, (size_t)Nn * 2 * 4, stream);

  k1_gemm<<<1024, 128, 0, stream>>>(x, W, bW, att, hb, ai, aj, Nn);
  k_sden<<<1024, 256, 0, stream>>>(ei, eatt, att, bemb, (const float2*)ai,
                                   (const float2*)aj, sden, Ee);
  k_bin<<<NBLK, 256, 0, stream>>>(ei, eatt, rec, cnt_tbl, base_tbl, Ee, NCB);
  k_segoff_a<<<NCB, 256, 0, stream>>>(cnt_tbl, segdst, btot, NCB, NBLK);
  k_segoff_b<<<1, 512, 0, stream>>>(btot, coarse_base, NCB, Ee);
  k_sort<<<NCB, 256, 0, stream>>>(rec, cnt_tbl, base_tbl, segdst, coarse_base,
                                  (const float2*)ai, (const float2*)aj,
                                  (const float2*)sden, att, bemb, eix2, alpha2,
                                  off, Nn, NCB, NBLK, Ee);
  k_gather<<<(Nn + 3) / 4, 256, 0, stream>>>(eix2, alpha2, off, hb, bemb, bias,
                                             (float*)d_out, Nn);
}

// Round 14
// 451.611 us; speedup vs baseline: 1.6668x; 1.0236x over previous
//
#include <hip/hip_runtime.h>
#include <hip/hip_bf16.h>
#include <math.h>

#define NEG_SLOPE 0.2f
#define CHUNK 2048      // edges per k_bin block
#define NPB2 128        // nodes per coarse bucket
#define SCAP 5120       // k_sort LDS capacity (bucket mean ~4092, sd ~64)
#define NREP 8          // sden replicas (one per XCD via blockIdx%8)

__device__ __forceinline__ unsigned f2bf(float f) {
  unsigned u = __float_as_uint(f);
  return (u + 0x7fffu + ((u >> 16) & 1u)) >> 16;  // RNE
}

// ---------------------------------------------------------------------------
// K1: h = x @ W + b_W (registers), emit:
//   hb [N][64] uint : {bf16 h(head0,d) lo | bf16 h(head1,d) hi}
//   ai [N][2], aj [N][2] : per-node attention scalars
// ---------------------------------------------------------------------------
__global__ __launch_bounds__(128) void k1_gemm(
    const float* __restrict__ x, const float* __restrict__ W,
    const float* __restrict__ bW, const float* __restrict__ att,
    unsigned int* __restrict__ hb, float* __restrict__ ai,
    float* __restrict__ aj, int Nn) {
  __shared__ float Ws[64 * 128];
  __shared__ float xs[64];
  __shared__ float bs[128];
  __shared__ float atts[256];
  __shared__ float hsh[128];
  int t = threadIdx.x;
  for (int i = t; i < 64 * 128; i += 128) Ws[i] = W[i];
  bs[t] = bW[t];
  atts[t] = att[t];
  atts[128 + t] = att[128 + t];
  __syncthreads();
  int head = t >> 6;
  int lane = t & 63;
  for (int row = blockIdx.x; row < Nn; row += gridDim.x) {
    if (t < 64) xs[t] = x[(size_t)row * 64 + t];
    __syncthreads();
    float acc = bs[t];
#pragma unroll
    for (int k = 0; k < 64; ++k) acc += xs[k] * Ws[k * 128 + t];
    hsh[t] = acc;
    float ti = atts[head * 128 + lane] * acc;
    float tj = atts[head * 128 + 64 + lane] * acc;
#pragma unroll
    for (int off = 32; off > 0; off >>= 1) {
      ti += __shfl_down(ti, off, 64);
      tj += __shfl_down(tj, off, 64);
    }
    if (lane == 0) { ai[row * 2 + head] = ti; aj[row * 2 + head] = tj; }
    __syncthreads();
    if (t < 64)
      hb[(size_t)row * 64 + t] = f2bf(hsh[t]) | (f2bf(hsh[64 + t]) << 16);
  }
}

// ---------------------------------------------------------------------------
// K_sden: softmax denominators into XCD-PRIVATE replicas (blockIdx%8 tracks
// the round-robin workgroup->XCD dispatch) -> atomics stay XCD-local in L2,
// no cross-XCD line ping-pong, HBM write = dirty replicas (~3.2 MB) not
// 3.2M x 32 B sectors.
// ---------------------------------------------------------------------------
__global__ __launch_bounds__(256) void k_sden(
    const int* __restrict__ ei, const int* __restrict__ eattr,
    const float* __restrict__ att, const float* __restrict__ bemb,
    const float2* __restrict__ ai2, const float2* __restrict__ aj2,
    float* __restrict__ sdenP, int Ee, int Nn) {
  __shared__ float tbl[30];
  int t = threadIdx.x;
  if (t < 30) {
    int f = t / 10, rem = t % 10, c = rem >> 1, hh = rem & 1;
    float sacc = 0.f;
    for (int d = 0; d < 64; ++d)
      sacc += att[hh * 128 + 64 + d] * bemb[(f * 5 + c) * 128 + hh * 64 + d];
    tbl[t] = sacc;
  }
  __syncthreads();
  float* my = sdenP + (size_t)(blockIdx.x & (NREP - 1)) * Nn * 2;
  int stride = gridDim.x * 256;
  for (int e = blockIdx.x * 256 + t; e < Ee; e += stride) {
    int dst = __builtin_nontemporal_load(&ei[Ee + e]);
    int src = __builtin_nontemporal_load(&ei[e]);
    int a0 = __builtin_nontemporal_load(&eattr[e * 3]);
    int a1 = __builtin_nontemporal_load(&eattr[e * 3 + 1]);
    int a2 = __builtin_nontemporal_load(&eattr[e * 3 + 2]);
    float2 aiv = ai2[dst];
    float2 ajv = aj2[src];
    float lg0 = aiv.x + ajv.x + tbl[a0 * 2] + tbl[10 + a1 * 2] + tbl[20 + a2 * 2];
    float lg1 = aiv.y + ajv.y + tbl[a0 * 2 + 1] + tbl[10 + a1 * 2 + 1] +
                tbl[20 + a2 * 2 + 1];
    lg0 = lg0 >= 0.f ? lg0 : NEG_SLOPE * lg0;
    lg1 = lg1 >= 0.f ? lg1 : NEG_SLOPE * lg1;
    atomicAdd(&my[src * 2], __expf(lg0));
    atomicAdd(&my[src * 2 + 1], __expf(lg1));
  }
}

// ---------------------------------------------------------------------------
// K_sred: sum the NREP replicas -> sden. Coalesced.
// ---------------------------------------------------------------------------
__global__ __launch_bounds__(256) void k_sred(
    const float* __restrict__ sdenP, float* __restrict__ sden, int Nn) {
  int total = Nn * 2;
  int i = blockIdx.x * 256 + threadIdx.x;
  if (i >= total) return;
  float s = 0.f;
#pragma unroll
  for (int r = 0; r < NREP; ++r) s += sdenP[(size_t)r * total + i];
  sden[i] = s;
}

// ---------------------------------------------------------------------------
// K_bin: PURE binning (no float math). Each block owns a 2048-edge chunk and
// a private contiguous window of rec; multi-split by coarse bucket cb=dst>>7
// staged in LDS, flushed sequentially. Edges held in registers (one pass).
// Record: {src:16 | (a0+5a1+25a2)<<16 | (dst&127)<<23}.
// ---------------------------------------------------------------------------
__global__ __launch_bounds__(256) void k_bin(
    const int* __restrict__ ei, const int* __restrict__ eattr,
    unsigned int* __restrict__ rec, int* __restrict__ cnt_tbl,
    int* __restrict__ base_tbl, int Ee, int NCB) {
  __shared__ unsigned sbuf[CHUNK];  // 8 KB staging
  __shared__ int hist[512];
  __shared__ int cur[512];
  int t = threadIdx.x;
  for (int i = t; i < NCB; i += 256) hist[i] = 0;
  __syncthreads();
  int start = blockIdx.x * CHUNK;
  int end = min(start + CHUNK, Ee);
  int cnt = end - start;
  int cbv[CHUNK / 256];
  unsigned pkv[CHUNK / 256];
  int nk = 0;
  for (int e = start + t; e < end; e += 256, ++nk) {
    int dst = __builtin_nontemporal_load(&ei[Ee + e]);
    int src = __builtin_nontemporal_load(&ei[e]);
    int a0 = __builtin_nontemporal_load(&eattr[e * 3]);
    int a1 = __builtin_nontemporal_load(&eattr[e * 3 + 1]);
    int a2 = __builtin_nontemporal_load(&eattr[e * 3 + 2]);
    cbv[nk] = dst >> 7;
    pkv[nk] = (unsigned)src | ((unsigned)(a0 + 5 * a1 + 25 * a2) << 16) |
              ((unsigned)(dst & 127) << 23);
    atomicAdd(&hist[dst >> 7], 1);
  }
  __syncthreads();
  if (t == 0) {
    int s = 0;
    for (int i = 0; i < NCB; ++i) { cur[i] = s; s += hist[i]; }
  }
  __syncthreads();
  for (int i = t; i < NCB; i += 256) {
    cnt_tbl[blockIdx.x * NCB + i] = hist[i];
    base_tbl[blockIdx.x * NCB + i] = cur[i];
  }
  __syncthreads();
  for (int k = 0; k < nk; ++k) {
    int pos = atomicAdd(&cur[cbv[k]], 1);
    sbuf[pos] = pkv[k];
  }
  __syncthreads();
  for (int i = t; i < cnt; i += 256)
    __builtin_nontemporal_store(sbuf[i], &rec[start + i]);
}

// ---------------------------------------------------------------------------
// K_segoff_a: PARALLEL per-bucket segment-offset scan. One block per coarse
// bucket cb; 256-thread exclusive scan over the NBLK per-block counts ->
// segdst[cb][blk] (coalesced) + bucket total.
// ---------------------------------------------------------------------------
__global__ __launch_bounds__(256) void k_segoff_a(
    const int* __restrict__ cnt_tbl, int* __restrict__ segdst,
    int* __restrict__ btot, int NCB, int NBLK) {
  __shared__ int s[256];
  int t = threadIdx.x, cb = blockIdx.x;
  int per = (NBLK + 255) / 256;  // 4 at NBLK=782
  int loc[8];
  int sum = 0;
  for (int j = 0; j < per; ++j) {
    int blk = t * per + j;
    int v = (blk < NBLK) ? cnt_tbl[blk * NCB + cb] : 0;
    loc[j] = sum;
    sum += v;
  }
  s[t] = sum;
  __syncthreads();
#pragma unroll
  for (int o = 1; o < 256; o <<= 1) {
    int xv = (t >= o) ? s[t - o] : 0;
    __syncthreads();
    s[t] += xv;
    __syncthreads();
  }
  int excl = s[t] - sum;
  for (int j = 0; j < per; ++j) {
    int blk = t * per + j;
    if (blk < NBLK) segdst[cb * NBLK + blk] = excl + loc[j];
  }
  if (t == 255) btot[cb] = s[255];
}

// ---------------------------------------------------------------------------
// K_segoff_b: tiny single-block exclusive scan over bucket totals.
// ---------------------------------------------------------------------------
__global__ __launch_bounds__(512) void k_segoff_b(
    const int* __restrict__ btot, int* __restrict__ coarse_base, int NCB, int Ee) {
  __shared__ int s[512];
  int t = threadIdx.x;
  int v = (t < NCB) ? btot[t] : 0;
  s[t] = v;
  __syncthreads();
#pragma unroll
  for (int o = 1; o < 512; o <<= 1) {
    int xv = (t >= o) ? s[t - o] : 0;
    __syncthreads();
    s[t] += xv;
    __syncthreads();
  }
  if (t < NCB) coarse_base[t] = s[t] - v;
  if (t == 0) coarse_base[NCB] = Ee;
}

// ---------------------------------------------------------------------------
// K_sort: one block per coarse bucket (128 nodes, ~4096 edges, 40 KB LDS ->
// ~3 blocks/CU). Per-THREAD segment staging, LDS counting sort by node-local
// id, then a 4-deep unrolled sequential output phase computing final alpha
// (batched random aj/sden reads) with fully coalesced eix2/alpha2 writes.
// ---------------------------------------------------------------------------
__global__ __launch_bounds__(256) void k_sort(
    const unsigned int* __restrict__ rec, const int* __restrict__ cnt_tbl,
    const int* __restrict__ base_tbl, const int* __restrict__ segdst,
    const int* __restrict__ coarse_base, const float2* __restrict__ ai2,
    const float2* __restrict__ aj2, const float2* __restrict__ sd2,
    const float* __restrict__ att, const float* __restrict__ bemb,
    unsigned int* __restrict__ eix2, float2* __restrict__ alpha2,
    int* __restrict__ off, int Nn, int NCB, int NBLK, int Ee) {
  __shared__ unsigned ubuf[SCAP];   // 20 KB
  __shared__ unsigned ubuf2[SCAP];  // 20 KB
  __shared__ int hist[NPB2], basex[NPB2], curx[NPB2];
  __shared__ float tbl[30];
  __shared__ float2 ais[NPB2];
  int t = threadIdx.x;
  int cb = blockIdx.x;
  if (t < 30) {
    int f = t / 10, rem = t % 10, c = rem >> 1, hh = rem & 1;
    float sacc = 0.f;
    for (int d = 0; d < 64; ++d)
      sacc += att[hh * 128 + 64 + d] * bemb[(f * 5 + c) * 128 + hh * 64 + d];
    tbl[t] = sacc;
  }
  int node0 = cb << 7;
  if (t < NPB2) {
    hist[t] = 0;
    if (node0 + t < Nn) ais[t] = ai2[node0 + t];
  }
  int gbase = coarse_base[cb];
  int total = coarse_base[cb + 1] - gbase;
  __syncthreads();
  bool fits = (total <= SCAP);

  if (fits) {
    // stage: thread t copies segments blk = t, t+256, ...
    for (int blk = t; blk < NBLK; blk += 256) {
      int len = cnt_tbl[blk * NCB + cb];
      if (!len) continue;
      int sp = blk * CHUNK + base_tbl[blk * NCB + cb];
      int dp = segdst[cb * NBLK + blk];
      for (int j = 0; j < len; ++j) ubuf[dp + j] = rec[sp + j];
    }
    __syncthreads();
    for (int i = t; i < total; i += 256)
      atomicAdd(&hist[(ubuf[i] >> 23) & 127], 1);
    __syncthreads();
    if (t == 0) {
      int s = 0;
      for (int i = 0; i < NPB2; ++i) { basex[i] = s; s += hist[i]; }
    }
    __syncthreads();
    if (t < NPB2) {
      curx[t] = basex[t];
      if (node0 + t < Nn) off[node0 + t] = gbase + basex[t];
    }
    if (cb == 0 && t == 0) off[Nn] = Ee;
    __syncthreads();
    for (int i = t; i < total; i += 256) {
      unsigned u = ubuf[i];
      int pos = atomicAdd(&curx[(u >> 23) & 127], 1);
      ubuf2[pos] = u;
    }
    __syncthreads();

#define OUT_BODY(I, U, AJV, SDV)                                               \
    {                                                                          \
      int src = (U) & 0xFFFF;                                                  \
      int c012 = ((U) >> 16) & 127;                                            \
      int dl = ((U) >> 23) & 127;                                              \
      int a0 = c012 % 5, a1 = (c012 / 5) % 5, a2 = c012 / 25;                  \
      float2 aiv = ais[dl];                                                    \
      float lg0 = aiv.x + AJV.x + tbl[a0 * 2] + tbl[10 + a1 * 2] +             \
                  tbl[20 + a2 * 2];                                            \
      float lg1 = aiv.y + AJV.y + tbl[a0 * 2 + 1] + tbl[10 + a1 * 2 + 1] +     \
                  tbl[20 + a2 * 2 + 1];                                        \
      lg0 = lg0 >= 0.f ? lg0 : NEG_SLOPE * lg0;                                \
      lg1 = lg1 >= 0.f ? lg1 : NEG_SLOPE * lg1;                                \
      eix2[gbase + (I)] = (unsigned)src | ((unsigned)a0 << 16) |               \
                          ((unsigned)a1 << 19) | ((unsigned)a2 << 22);         \
      alpha2[gbase + (I)] = make_float2(__expf(lg0) / (SDV.x + 1e-16f),        \
                                        __expf(lg1) / (SDV.y + 1e-16f));       \
    }

    int i = t;
    for (; i + 3 * 256 < total; i += 4 * 256) {
      unsigned u[4];
      float2 ajv[4], sdv[4];
#pragma unroll
      for (int k = 0; k < 4; ++k) u[k] = ubuf2[i + k * 256];
#pragma unroll
      for (int k = 0; k < 4; ++k) ajv[k] = aj2[u[k] & 0xFFFF];
#pragma unroll
      for (int k = 0; k < 4; ++k) sdv[k] = sd2[u[k] & 0xFFFF];
#pragma unroll
      for (int k = 0; k < 4; ++k) OUT_BODY(i + k * 256, u[k], ajv[k], sdv[k])
    }
    for (; i < total; i += 256) {
      unsigned u = ubuf2[i];
      float2 ajv = aj2[u & 0xFFFF];
      float2 sdv = sd2[u & 0xFFFF];
      OUT_BODY(i, u, ajv, sdv)
    }
#undef OUT_BODY
  } else {
    // fallback (statistically unreachable): global-read path
    for (int blk = t; blk < NBLK; blk += 256) {
      int len = cnt_tbl[blk * NCB + cb];
      int sp = blk * CHUNK + base_tbl[blk * NCB + cb];
      for (int j = 0; j < len; ++j)
        atomicAdd(&hist[(rec[sp + j] >> 23) & 127], 1);
    }
    __syncthreads();
    if (t == 0) {
      int s = 0;
      for (int i = 0; i < NPB2; ++i) { basex[i] = s; s += hist[i]; }
    }
    __syncthreads();
    if (t < NPB2) {
      curx[t] = basex[t];
      if (node0 + t < Nn) off[node0 + t] = gbase + basex[t];
    }
    if (cb == 0 && t == 0) off[Nn] = Ee;
    __syncthreads();
    for (int blk = t; blk < NBLK; blk += 256) {
      int len = cnt_tbl[blk * NCB + cb];
      int sp = blk * CHUNK + base_tbl[blk * NCB + cb];
      for (int j = 0; j < len; ++j) {
        unsigned u = rec[sp + j];
        int src = u & 0xFFFF;
        int c012 = (u >> 16) & 127;
        int dl = (u >> 23) & 127;
        int a0 = c012 % 5, a1 = (c012 / 5) % 5, a2 = c012 / 25;
        float2 aiv = ais[dl];
        float2 ajv = aj2[src];
        float2 sdv = sd2[src];
        float lg0 = aiv.x + ajv.x + tbl[a0 * 2] + tbl[10 + a1 * 2] + tbl[20 + a2 * 2];
        float lg1 = aiv.y + ajv.y + tbl[a0 * 2 + 1] + tbl[10 + a1 * 2 + 1] +
                    tbl[20 + a2 * 2 + 1];
        lg0 = lg0 >= 0.f ? lg0 : NEG_SLOPE * lg0;
        lg1 = lg1 >= 0.f ? lg1 : NEG_SLOPE * lg1;
        int pos = gbase + atomicAdd(&curx[dl], 1);
        eix2[pos] = (unsigned)src | ((unsigned)a0 << 16) | ((unsigned)a1 << 19) |
                    ((unsigned)a2 << 22);
        alpha2[pos] = make_float2(__expf(lg0) / (sdv.x + 1e-16f),
                                  __expf(lg1) / (sdv.y + 1e-16f));
      }
    }
  }
}

// ---------------------------------------------------------------------------
// K_gather: one wave per dst node, lane = d. Per edge: sequential rec+alpha
// reads, one coalesced hb gather, 2 FMA + predicated w-update. Edge-emb term
// hoisted: lanes 0..29 accumulate w[f,c,h]; epilogue adds 15-term weighted
// bemb sum.
// ---------------------------------------------------------------------------
__global__ __launch_bounds__(256) void k_gather(
    const unsigned int* __restrict__ eix, const float2* __restrict__ alpha2,
    const int* __restrict__ off, const unsigned int* __restrict__ hb,
    const float* __restrict__ bemb, const float* __restrict__ bias,
    float* __restrict__ out, int Nn) {
  __shared__ float bembs[15 * 128];  // [f*5+c][128]
  __shared__ float wsm[4][32];
  int t = threadIdx.x;
  for (int i = t; i < 15 * 128; i += 256) bembs[i] = bemb[i];
  __syncthreads();
  int wave = t >> 6, lane = t & 63;
  int n = blockIdx.x * 4 + wave;
  if (n >= Nn) return;
  int p0 = off[n], p1 = off[n + 1];
  int myf = lane / 10;
  int myc = (lane % 10) >> 1;
  bool myh = (lane & 1) != 0;
  bool active = lane < 30;
  float w = 0.f;
  float acc0 = 0.f, acc1 = 0.f;

#define EDGE_BODY(U, HV, AL)                                                   \
  {                                                                            \
    acc0 += AL.x * __uint_as_float(HV << 16);                                  \
    acc1 += AL.y * __uint_as_float(HV & 0xffff0000u);                          \
    int a0 = (U >> 16) & 7, a1 = (U >> 19) & 7, a2 = (U >> 22) & 7;            \
    int sel = myf == 0 ? a0 : (myf == 1 ? a1 : a2);                            \
    w += (active && myc == sel) ? (myh ? AL.y : AL.x) : 0.f;                   \
  }

  int p = p0;
  for (; p + 8 <= p1; p += 8) {
    unsigned u[8], hv[8];
    float2 al[8];
#pragma unroll
    for (int k = 0; k < 8; ++k) u[k] = eix[p + k];
#pragma unroll
    for (int k = 0; k < 8; ++k) al[k] = alpha2[p + k];
#pragma unroll
    for (int k = 0; k < 8; ++k)
      hv[k] = hb[(size_t)(u[k] & 0xFFFF) * 64 + lane];
#pragma unroll
    for (int k = 0; k < 8; ++k) EDGE_BODY(u[k], hv[k], al[k])
  }
  for (; p < p1; ++p) {
    unsigned u0 = eix[p];
    float2 al0 = alpha2[p];
    unsigned hv0 = hb[(size_t)(u0 & 0xFFFF) * 64 + lane];
    EDGE_BODY(u0, hv0, al0)
  }
#undef EDGE_BODY

  if (active) wsm[wave][lane] = w;  // same-wave LDS ops are in-order
#pragma unroll
  for (int k = 0; k < 15; ++k) {
    acc0 += wsm[wave][k * 2] * bembs[k * 128 + lane];
    acc1 += wsm[wave][k * 2 + 1] * bembs[k * 128 + 64 + lane];
  }
  out[(size_t)n * 64 + lane] = 0.5f * (acc0 + acc1) + bias[lane];
}

extern "C" void kernel_launch(void* const* d_in, const int* in_sizes, int n_in,
                              void* d_out, int out_size, void* d_ws, size_t ws_size,
                              hipStream_t stream) {
  const float* x    = (const float*)d_in[0];
  const int*   ei   = (const int*)d_in[1];
  const int*   eatt = (const int*)d_in[2];
  const float* W    = (const float*)d_in[3];
  const float* bW   = (const float*)d_in[4];
  const float* att  = (const float*)d_in[5];
  const float* bias = (const float*)d_in[6];
  const float* bemb = (const float*)d_in[7];
  int Nn = in_sizes[0] / 64;
  int Ee = in_sizes[1] / 2;
  int NCB = (Nn + NPB2 - 1) / NPB2;            // 391 coarse buckets (128 nodes)
  int NBLK = (Ee + CHUNK - 1) / CHUNK;         // 782 bin blocks

  char* ws = (char*)d_ws;
  ws = (char*)(((uintptr_t)ws + 15) & ~(uintptr_t)15);
  float* aj = (float*)ws;                 ws += (size_t)Nn * 2 * 4;
  float* sden = (float*)ws;               ws += (size_t)Nn * 2 * 4;
  float* ai = (float*)ws;                 ws += (size_t)Nn * 2 * 4;
  float* sdenP = (float*)ws;              ws += (size_t)NREP * Nn * 2 * 4;
  unsigned int* hb = (unsigned int*)ws;   ws += (size_t)Nn * 64 * 4;
  unsigned int* rec = (unsigned int*)ws;  ws += (size_t)NBLK * CHUNK * 4;
  unsigned int* eix2 = (unsigned int*)ws; ws += (size_t)Ee * 4;
  float2* alpha2 = (float2*)ws;           ws += (size_t)Ee * 8;
  int* off = (int*)ws;                    ws += (size_t)(Nn + 1) * 4;
  int* cnt_tbl = (int*)ws;                ws += (size_t)NBLK * NCB * 4;
  int* base_tbl = (int*)ws;               ws += (size_t)NBLK * NCB * 4;
  int* segdst = (int*)ws;                 ws += (size_t)NCB * NBLK * 4;
  int* coarse_base = (int*)ws;            ws += (size_t)(NCB + 1) * 4;
  int* btot = (int*)ws;                   ws += (size_t)NCB * 4;

  hipMemsetAsync(sdenP, 0, (size_t)NREP * Nn * 2 * 4, stream);

  k1_gemm<<<1024, 128, 0, stream>>>(x, W, bW, att, hb, ai, aj, Nn);
  k_sden<<<1024, 256, 0, stream>>>(ei, eatt, att, bemb, (const float2*)ai,
                                   (const float2*)aj, sdenP, Ee, Nn);
  k_sred<<<(Nn * 2 + 255) / 256, 256, 0, stream>>>(sdenP, sden, Nn);
  k_bin<<<NBLK, 256, 0, stream>>>(ei, eatt, rec, cnt_tbl, base_tbl, Ee, NCB);
  k_segoff_a<<<NCB, 256, 0, stream>>>(cnt_tbl, segdst, btot, NCB, NBLK);
  k_segoff_b<<<1, 512, 0, stream>>>(btot, coarse_base, NCB, Ee);
  k_sort<<<NCB, 256, 0, stream>>>(rec, cnt_tbl, base_tbl, segdst, coarse_base,
                                  (const float2*)ai, (const float2*)aj,
                                  (const float2*)sden, att, bemb, eix2, alpha2,
                                  off, Nn, NCB, NBLK, Ee);
  k_gather<<<(Nn + 3) / 4, 256, 0, stream>>>(eix2, alpha2, off, hb, bemb, bias,
                                             (float*)d_out, Nn);
}

// Round 15
// 334.303 us; speedup vs baseline: 2.2516x; 1.3509x over previous
//
#include <hip/hip_runtime.h>
#include <hip/hip_bf16.h>
#include <math.h>

#define NEG_SLOPE 0.2f
#define CHUNK 2048      // edges per k_bin block
#define NPB2 128        // nodes per coarse bucket
#define SCAP 5120       // LDS record capacity (bucket mean ~4092, sd ~64)

__device__ __forceinline__ unsigned f2bf(float f) {
  unsigned u = __float_as_uint(f);
  return (u + 0x7fffu + ((u >> 16) & 1u)) >> 16;  // RNE
}

// ---------------------------------------------------------------------------
// K1: h = x @ W + b_W (registers), emit:
//   hb [N][64] uint : {bf16 h(head0,d) lo | bf16 h(head1,d) hi}
//   ai [N][2], aj [N][2] : per-node attention scalars
// ---------------------------------------------------------------------------
__global__ __launch_bounds__(128) void k1_gemm(
    const float* __restrict__ x, const float* __restrict__ W,
    const float* __restrict__ bW, const float* __restrict__ att,
    unsigned int* __restrict__ hb, float* __restrict__ ai,
    float* __restrict__ aj, int Nn) {
  __shared__ float Ws[64 * 128];
  __shared__ float xs[64];
  __shared__ float bs[128];
  __shared__ float atts[256];
  __shared__ float hsh[128];
  int t = threadIdx.x;
  for (int i = t; i < 64 * 128; i += 128) Ws[i] = W[i];
  bs[t] = bW[t];
  atts[t] = att[t];
  atts[128 + t] = att[128 + t];
  __syncthreads();
  int head = t >> 6;
  int lane = t & 63;
  for (int row = blockIdx.x; row < Nn; row += gridDim.x) {
    if (t < 64) xs[t] = x[(size_t)row * 64 + t];
    __syncthreads();
    float acc = bs[t];
#pragma unroll
    for (int k = 0; k < 64; ++k) acc += xs[k] * Ws[k * 128 + t];
    hsh[t] = acc;
    float ti = atts[head * 128 + lane] * acc;
    float tj = atts[head * 128 + 64 + lane] * acc;
#pragma unroll
    for (int off = 32; off > 0; off >>= 1) {
      ti += __shfl_down(ti, off, 64);
      tj += __shfl_down(tj, off, 64);
    }
    if (lane == 0) { ai[row * 2 + head] = ti; aj[row * 2 + head] = tj; }
    __syncthreads();
    if (t < 64)
      hb[(size_t)row * 64 + t] = f2bf(hsh[t]) | (f2bf(hsh[64 + t]) << 16);
  }
}

// ---------------------------------------------------------------------------
// K_bin: DUAL multi-split (no float math, no global atomics). Each block owns
// a 2048-edge chunk and TWO private contiguous windows:
//   rec     binned by dst coarse bucket: {src:16 | c012<<16 | (dst&127)<<23}
//   rec_src binned by src coarse bucket: {dst:17 | (src&127)<<17 | c012<<24}
// Both LDS-staged and flushed sequentially (no scattered global stores).
// ---------------------------------------------------------------------------
__global__ __launch_bounds__(256) void k_bin(
    const int* __restrict__ ei, const int* __restrict__ eattr,
    unsigned int* __restrict__ rec, int* __restrict__ cnt_tbl,
    int* __restrict__ base_tbl, unsigned int* __restrict__ rec_src,
    int* __restrict__ cnt_tbl2, int* __restrict__ base_tbl2, int Ee, int NCB) {
  __shared__ unsigned sbuf[CHUNK];   // 8 KB
  __shared__ unsigned sbuf2[CHUNK];  // 8 KB
  __shared__ int hist[512], cur[512], hist2[512], cur2[512];
  int t = threadIdx.x;
  for (int i = t; i < NCB; i += 256) { hist[i] = 0; hist2[i] = 0; }
  __syncthreads();
  int start = blockIdx.x * CHUNK;
  int end = min(start + CHUNK, Ee);
  int cnt = end - start;
  int cbv[CHUNK / 256], cb2v[CHUNK / 256];
  unsigned pkv[CHUNK / 256], pk2v[CHUNK / 256];
  int nk = 0;
  for (int e = start + t; e < end; e += 256, ++nk) {
    int dst = __builtin_nontemporal_load(&ei[Ee + e]);
    int src = __builtin_nontemporal_load(&ei[e]);
    int a0 = __builtin_nontemporal_load(&eattr[e * 3]);
    int a1 = __builtin_nontemporal_load(&eattr[e * 3 + 1]);
    int a2 = __builtin_nontemporal_load(&eattr[e * 3 + 2]);
    unsigned c012 = (unsigned)(a0 + 5 * a1 + 25 * a2);
    cbv[nk] = dst >> 7;
    pkv[nk] = (unsigned)src | (c012 << 16) | ((unsigned)(dst & 127) << 23);
    cb2v[nk] = src >> 7;
    pk2v[nk] = (unsigned)dst | ((unsigned)(src & 127) << 17) | (c012 << 24);
    atomicAdd(&hist[dst >> 7], 1);
    atomicAdd(&hist2[src >> 7], 1);
  }
  __syncthreads();
  if (t == 0) {
    int s = 0;
    for (int i = 0; i < NCB; ++i) { cur[i] = s; s += hist[i]; }
  }
  if (t == 64) {
    int s = 0;
    for (int i = 0; i < NCB; ++i) { cur2[i] = s; s += hist2[i]; }
  }
  __syncthreads();
  for (int i = t; i < NCB; i += 256) {
    cnt_tbl[blockIdx.x * NCB + i] = hist[i];
    base_tbl[blockIdx.x * NCB + i] = cur[i];
    cnt_tbl2[blockIdx.x * NCB + i] = hist2[i];
    base_tbl2[blockIdx.x * NCB + i] = cur2[i];
  }
  __syncthreads();
  for (int k = 0; k < nk; ++k) {
    int pos = atomicAdd(&cur[cbv[k]], 1);
    sbuf[pos] = pkv[k];
    int pos2 = atomicAdd(&cur2[cb2v[k]], 1);
    sbuf2[pos2] = pk2v[k];
  }
  __syncthreads();
  for (int i = t; i < cnt; i += 256) {
    __builtin_nontemporal_store(sbuf[i], &rec[start + i]);
    __builtin_nontemporal_store(sbuf2[i], &rec_src[start + i]);
  }
}

// ---------------------------------------------------------------------------
// K_segoff_a: PARALLEL per-bucket segment-offset scan (generic, used for both
// the dst and src tables). One block per coarse bucket; scan over NBLK counts
// -> segdst[cb][blk] + bucket total.
// ---------------------------------------------------------------------------
__global__ __launch_bounds__(256) void k_segoff_a(
    const int* __restrict__ cnt_tbl, int* __restrict__ segdst,
    int* __restrict__ btot, int NCB, int NBLK) {
  __shared__ int s[256];
  int t = threadIdx.x, cb = blockIdx.x;
  int per = (NBLK + 255) / 256;
  int loc[8];
  int sum = 0;
  for (int j = 0; j < per; ++j) {
    int blk = t * per + j;
    int v = (blk < NBLK) ? cnt_tbl[blk * NCB + cb] : 0;
    loc[j] = sum;
    sum += v;
  }
  s[t] = sum;
  __syncthreads();
#pragma unroll
  for (int o = 1; o < 256; o <<= 1) {
    int xv = (t >= o) ? s[t - o] : 0;
    __syncthreads();
    s[t] += xv;
    __syncthreads();
  }
  int excl = s[t] - sum;
  for (int j = 0; j < per; ++j) {
    int blk = t * per + j;
    if (blk < NBLK) segdst[cb * NBLK + blk] = excl + loc[j];
  }
  if (t == 255) btot[cb] = s[255];
}

// ---------------------------------------------------------------------------
// K_segoff_b: tiny single-block exclusive scan over dst bucket totals.
// ---------------------------------------------------------------------------
__global__ __launch_bounds__(512) void k_segoff_b(
    const int* __restrict__ btot, int* __restrict__ coarse_base, int NCB, int Ee) {
  __shared__ int s[512];
  int t = threadIdx.x;
  int v = (t < NCB) ? btot[t] : 0;
  s[t] = v;
  __syncthreads();
#pragma unroll
  for (int o = 1; o < 512; o <<= 1) {
    int xv = (t >= o) ? s[t - o] : 0;
    __syncthreads();
    s[t] += xv;
    __syncthreads();
  }
  if (t < NCB) coarse_base[t] = s[t] - v;
  if (t == 0) coarse_base[NCB] = Ee;
}

// ---------------------------------------------------------------------------
// K_sacc: softmax denominators WITHOUT global atomics. One block per SRC
// coarse bucket: stage the bucket's src-binned records to LDS, compute
// exp(leaky(lg)) (aj staged in LDS; ai2[dst] random L2 reads, 4-deep
// batched), accumulate into a 1 KB LDS sden tile, write sden coalesced.
// ---------------------------------------------------------------------------
__global__ __launch_bounds__(256) void k_sacc(
    const unsigned int* __restrict__ rec_src, const int* __restrict__ cnt_tbl2,
    const int* __restrict__ base_tbl2, const int* __restrict__ segdst2,
    const int* __restrict__ btot2, const float2* __restrict__ ai2,
    const float2* __restrict__ aj2, const float* __restrict__ att,
    const float* __restrict__ bemb, float* __restrict__ sden,
    int Nn, int NCB, int NBLK) {
  __shared__ unsigned ubuf[SCAP];       // 20 KB
  __shared__ float sdl[NPB2 * 2];       // 1 KB accumulators
  __shared__ float2 ajs[NPB2];
  __shared__ float tbl[30];
  int t = threadIdx.x;
  int cb = blockIdx.x;
  if (t < 30) {
    int f = t / 10, rem = t % 10, c = rem >> 1, hh = rem & 1;
    float sacc = 0.f;
    for (int d = 0; d < 64; ++d)
      sacc += att[hh * 128 + 64 + d] * bemb[(f * 5 + c) * 128 + hh * 64 + d];
    tbl[t] = sacc;
  }
  int node0 = cb << 7;
  if (t < NPB2 && node0 + t < Nn) ajs[t] = aj2[node0 + t];
  sdl[t] = 0.f;
  int total = btot2[cb];
  __syncthreads();
  bool fits = (total <= SCAP);

#define SACC_BODY(U, AIV)                                                      \
  {                                                                            \
    int sl = ((U) >> 17) & 127;                                                \
    int c012 = ((U) >> 24) & 127;                                              \
    int a0 = c012 % 5, a1 = (c012 / 5) % 5, a2 = c012 / 25;                    \
    float2 ajv = ajs[sl];                                                      \
    float lg0 = AIV.x + ajv.x + tbl[a0 * 2] + tbl[10 + a1 * 2] +               \
                tbl[20 + a2 * 2];                                              \
    float lg1 = AIV.y + ajv.y + tbl[a0 * 2 + 1] + tbl[10 + a1 * 2 + 1] +       \
                tbl[20 + a2 * 2 + 1];                                          \
    lg0 = lg0 >= 0.f ? lg0 : NEG_SLOPE * lg0;                                  \
    lg1 = lg1 >= 0.f ? lg1 : NEG_SLOPE * lg1;                                  \
    atomicAdd(&sdl[sl * 2], __expf(lg0));                                      \
    atomicAdd(&sdl[sl * 2 + 1], __expf(lg1));                                  \
  }

  if (fits) {
    for (int blk = t; blk < NBLK; blk += 256) {
      int len = cnt_tbl2[blk * NCB + cb];
      if (!len) continue;
      int sp = blk * CHUNK + base_tbl2[blk * NCB + cb];
      int dp = segdst2[cb * NBLK + blk];
      for (int j = 0; j < len; ++j) ubuf[dp + j] = rec_src[sp + j];
    }
    __syncthreads();
    int i = t;
    for (; i + 3 * 256 < total; i += 4 * 256) {
      unsigned u[4];
      float2 aiv[4];
#pragma unroll
      for (int k = 0; k < 4; ++k) u[k] = ubuf[i + k * 256];
#pragma unroll
      for (int k = 0; k < 4; ++k) aiv[k] = ai2[u[k] & 0x1FFFF];
#pragma unroll
      for (int k = 0; k < 4; ++k) SACC_BODY(u[k], aiv[k])
    }
    for (; i < total; i += 256) {
      unsigned u = ubuf[i];
      float2 aiv = ai2[u & 0x1FFFF];
      SACC_BODY(u, aiv)
    }
  } else {
    for (int blk = t; blk < NBLK; blk += 256) {
      int len = cnt_tbl2[blk * NCB + cb];
      int sp = blk * CHUNK + base_tbl2[blk * NCB + cb];
      for (int j = 0; j < len; ++j) {
        unsigned u = rec_src[sp + j];
        float2 aiv = ai2[u & 0x1FFFF];
        SACC_BODY(u, aiv)
      }
    }
  }
#undef SACC_BODY
  __syncthreads();
  if (node0 + (t >> 1) < Nn) sden[(size_t)node0 * 2 + t] = sdl[t];
}

// ---------------------------------------------------------------------------
// K_sort: one block per DST coarse bucket (128 nodes). LDS counting sort by
// node-local id, then 4-deep unrolled sequential output phase computing
// final alpha = exp/sden (batched random aj/sden reads), fully coalesced
// eix2/alpha2 writes + per-node CSR offsets.
// ---------------------------------------------------------------------------
__global__ __launch_bounds__(256) void k_sort(
    const unsigned int* __restrict__ rec, const int* __restrict__ cnt_tbl,
    const int* __restrict__ base_tbl, const int* __restrict__ segdst,
    const int* __restrict__ coarse_base, const float2* __restrict__ ai2,
    const float2* __restrict__ aj2, const float2* __restrict__ sd2,
    const float* __restrict__ att, const float* __restrict__ bemb,
    unsigned int* __restrict__ eix2, float2* __restrict__ alpha2,
    int* __restrict__ off, int Nn, int NCB, int NBLK, int Ee) {
  __shared__ unsigned ubuf[SCAP];   // 20 KB
  __shared__ unsigned ubuf2[SCAP];  // 20 KB
  __shared__ int hist[NPB2], basex[NPB2], curx[NPB2];
  __shared__ float tbl[30];
  __shared__ float2 ais[NPB2];
  int t = threadIdx.x;
  int cb = blockIdx.x;
  if (t < 30) {
    int f = t / 10, rem = t % 10, c = rem >> 1, hh = rem & 1;
    float sacc = 0.f;
    for (int d = 0; d < 64; ++d)
      sacc += att[hh * 128 + 64 + d] * bemb[(f * 5 + c) * 128 + hh * 64 + d];
    tbl[t] = sacc;
  }
  int node0 = cb << 7;
  if (t < NPB2) {
    hist[t] = 0;
    if (node0 + t < Nn) ais[t] = ai2[node0 + t];
  }
  int gbase = coarse_base[cb];
  int total = coarse_base[cb + 1] - gbase;
  __syncthreads();
  bool fits = (total <= SCAP);

  if (fits) {
    for (int blk = t; blk < NBLK; blk += 256) {
      int len = cnt_tbl[blk * NCB + cb];
      if (!len) continue;
      int sp = blk * CHUNK + base_tbl[blk * NCB + cb];
      int dp = segdst[cb * NBLK + blk];
      for (int j = 0; j < len; ++j) ubuf[dp + j] = rec[sp + j];
    }
    __syncthreads();
    for (int i = t; i < total; i += 256)
      atomicAdd(&hist[(ubuf[i] >> 23) & 127], 1);
    __syncthreads();
    if (t == 0) {
      int s = 0;
      for (int i = 0; i < NPB2; ++i) { basex[i] = s; s += hist[i]; }
    }
    __syncthreads();
    if (t < NPB2) {
      curx[t] = basex[t];
      if (node0 + t < Nn) off[node0 + t] = gbase + basex[t];
    }
    if (cb == 0 && t == 0) off[Nn] = Ee;
    __syncthreads();
    for (int i = t; i < total; i += 256) {
      unsigned u = ubuf[i];
      int pos = atomicAdd(&curx[(u >> 23) & 127], 1);
      ubuf2[pos] = u;
    }
    __syncthreads();

#define OUT_BODY(I, U, AJV, SDV)                                               \
    {                                                                          \
      int src = (U) & 0xFFFF;                                                  \
      int c012 = ((U) >> 16) & 127;                                            \
      int dl = ((U) >> 23) & 127;                                              \
      int a0 = c012 % 5, a1 = (c012 / 5) % 5, a2 = c012 / 25;                  \
      float2 aiv = ais[dl];                                                    \
      float lg0 = aiv.x + AJV.x + tbl[a0 * 2] + tbl[10 + a1 * 2] +             \
                  tbl[20 + a2 * 2];                                            \
      float lg1 = aiv.y + AJV.y + tbl[a0 * 2 + 1] + tbl[10 + a1 * 2 + 1] +     \
                  tbl[20 + a2 * 2 + 1];                                        \
      lg0 = lg0 >= 0.f ? lg0 : NEG_SLOPE * lg0;                                \
      lg1 = lg1 >= 0.f ? lg1 : NEG_SLOPE * lg1;                                \
      eix2[gbase + (I)] = (unsigned)src | ((unsigned)a0 << 16) |               \
                          ((unsigned)a1 << 19) | ((unsigned)a2 << 22);         \
      alpha2[gbase + (I)] = make_float2(__expf(lg0) / (SDV.x + 1e-16f),        \
                                        __expf(lg1) / (SDV.y + 1e-16f));       \
    }

    int i = t;
    for (; i + 3 * 256 < total; i += 4 * 256) {
      unsigned u[4];
      float2 ajv[4], sdv[4];
#pragma unroll
      for (int k = 0; k < 4; ++k) u[k] = ubuf2[i + k * 256];
#pragma unroll
      for (int k = 0; k < 4; ++k) ajv[k] = aj2[u[k] & 0xFFFF];
#pragma unroll
      for (int k = 0; k < 4; ++k) sdv[k] = sd2[u[k] & 0xFFFF];
#pragma unroll
      for (int k = 0; k < 4; ++k) OUT_BODY(i + k * 256, u[k], ajv[k], sdv[k])
    }
    for (; i < total; i += 256) {
      unsigned u = ubuf2[i];
      float2 ajv = aj2[u & 0xFFFF];
      float2 sdv = sd2[u & 0xFFFF];
      OUT_BODY(i, u, ajv, sdv)
    }
#undef OUT_BODY
  } else {
    // fallback (statistically unreachable): global-read path
    for (int blk = t; blk < NBLK; blk += 256) {
      int len = cnt_tbl[blk * NCB + cb];
      int sp = blk * CHUNK + base_tbl[blk * NCB + cb];
      for (int j = 0; j < len; ++j)
        atomicAdd(&hist[(rec[sp + j] >> 23) & 127], 1);
    }
    __syncthreads();
    if (t == 0) {
      int s = 0;
      for (int i = 0; i < NPB2; ++i) { basex[i] = s; s += hist[i]; }
    }
    __syncthreads();
    if (t < NPB2) {
      curx[t] = basex[t];
      if (node0 + t < Nn) off[node0 + t] = gbase + basex[t];
    }
    if (cb == 0 && t == 0) off[Nn] = Ee;
    __syncthreads();
    for (int blk = t; blk < NBLK; blk += 256) {
      int len = cnt_tbl[blk * NCB + cb];
      int sp = blk * CHUNK + base_tbl[blk * NCB + cb];
      for (int j = 0; j < len; ++j) {
        unsigned u = rec[sp + j];
        int src = u & 0xFFFF;
        int c012 = (u >> 16) & 127;
        int dl = (u >> 23) & 127;
        int a0 = c012 % 5, a1 = (c012 / 5) % 5, a2 = c012 / 25;
        float2 aiv = ais[dl];
        float2 ajv = aj2[src];
        float2 sdv = sd2[src];
        float lg0 = aiv.x + ajv.x + tbl[a0 * 2] + tbl[10 + a1 * 2] + tbl[20 + a2 * 2];
        float lg1 = aiv.y + ajv.y + tbl[a0 * 2 + 1] + tbl[10 + a1 * 2 + 1] +
                    tbl[20 + a2 * 2 + 1];
        lg0 = lg0 >= 0.f ? lg0 : NEG_SLOPE * lg0;
        lg1 = lg1 >= 0.f ? lg1 : NEG_SLOPE * lg1;
        int pos = gbase + atomicAdd(&curx[dl], 1);
        eix2[pos] = (unsigned)src | ((unsigned)a0 << 16) | ((unsigned)a1 << 19) |
                    ((unsigned)a2 << 22);
        alpha2[pos] = make_float2(__expf(lg0) / (sdv.x + 1e-16f),
                                  __expf(lg1) / (sdv.y + 1e-16f));
      }
    }
  }
}

// ---------------------------------------------------------------------------
// K_gather: one wave per dst node, lane = d. Per edge: sequential rec+alpha
// reads, one coalesced hb gather, 2 FMA + predicated w-update. Edge-emb term
// hoisted: lanes 0..29 accumulate w[f,c,h]; epilogue adds 15-term weighted
// bemb sum.
// ---------------------------------------------------------------------------
__global__ __launch_bounds__(256) void k_gather(
    const unsigned int* __restrict__ eix, const float2* __restrict__ alpha2,
    const int* __restrict__ off, const unsigned int* __restrict__ hb,
    const float* __restrict__ bemb, const float* __restrict__ bias,
    float* __restrict__ out, int Nn) {
  __shared__ float bembs[15 * 128];  // [f*5+c][128]
  __shared__ float wsm[4][32];
  int t = threadIdx.x;
  for (int i = t; i < 15 * 128; i += 256) bembs[i] = bemb[i];
  __syncthreads();
  int wave = t >> 6, lane = t & 63;
  int n = blockIdx.x * 4 + wave;
  if (n >= Nn) return;
  int p0 = off[n], p1 = off[n + 1];
  int myf = lane / 10;
  int myc = (lane % 10) >> 1;
  bool myh = (lane & 1) != 0;
  bool active = lane < 30;
  float w = 0.f;
  float acc0 = 0.f, acc1 = 0.f;

#define EDGE_BODY(U, HV, AL)                                                   \
  {                                                                            \
    acc0 += AL.x * __uint_as_float(HV << 16);                                  \
    acc1 += AL.y * __uint_as_float(HV & 0xffff0000u);                          \
    int a0 = (U >> 16) & 7, a1 = (U >> 19) & 7, a2 = (U >> 22) & 7;            \
    int sel = myf == 0 ? a0 : (myf == 1 ? a1 : a2);                            \
    w += (active && myc == sel) ? (myh ? AL.y : AL.x) : 0.f;                   \
  }

  int p = p0;
  for (; p + 8 <= p1; p += 8) {
    unsigned u[8], hv[8];
    float2 al[8];
#pragma unroll
    for (int k = 0; k < 8; ++k) u[k] = eix[p + k];
#pragma unroll
    for (int k = 0; k < 8; ++k) al[k] = alpha2[p + k];
#pragma unroll
    for (int k = 0; k < 8; ++k)
      hv[k] = hb[(size_t)(u[k] & 0xFFFF) * 64 + lane];
#pragma unroll
    for (int k = 0; k < 8; ++k) EDGE_BODY(u[k], hv[k], al[k])
  }
  for (; p < p1; ++p) {
    unsigned u0 = eix[p];
    float2 al0 = alpha2[p];
    unsigned hv0 = hb[(size_t)(u0 & 0xFFFF) * 64 + lane];
    EDGE_BODY(u0, hv0, al0)
  }
#undef EDGE_BODY

  if (active) wsm[wave][lane] = w;  // same-wave LDS ops are in-order
#pragma unroll
  for (int k = 0; k < 15; ++k) {
    acc0 += wsm[wave][k * 2] * bembs[k * 128 + lane];
    acc1 += wsm[wave][k * 2 + 1] * bembs[k * 128 + 64 + lane];
  }
  out[(size_t)n * 64 + lane] = 0.5f * (acc0 + acc1) + bias[lane];
}

extern "C" void kernel_launch(void* const* d_in, const int* in_sizes, int n_in,
                              void* d_out, int out_size, void* d_ws, size_t ws_size,
                              hipStream_t stream) {
  const float* x    = (const float*)d_in[0];
  const int*   ei   = (const int*)d_in[1];
  const int*   eatt = (const int*)d_in[2];
  const float* W    = (const float*)d_in[3];
  const float* bW   = (const float*)d_in[4];
  const float* att  = (const float*)d_in[5];
  const float* bias = (const float*)d_in[6];
  const float* bemb = (const float*)d_in[7];
  int Nn = in_sizes[0] / 64;
  int Ee = in_sizes[1] / 2;
  int NCB = (Nn + NPB2 - 1) / NPB2;            // 391 coarse buckets (128 nodes)
  int NBLK = (Ee + CHUNK - 1) / CHUNK;         // 782 bin blocks

  char* ws = (char*)d_ws;
  ws = (char*)(((uintptr_t)ws + 15) & ~(uintptr_t)15);
  float* aj = (float*)ws;                 ws += (size_t)Nn * 2 * 4;
  float* sden = (float*)ws;               ws += (size_t)Nn * 2 * 4;
  float* ai = (float*)ws;                 ws += (size_t)Nn * 2 * 4;
  unsigned int* hb = (unsigned int*)ws;   ws += (size_t)Nn * 64 * 4;
  unsigned int* rec = (unsigned int*)ws;  ws += (size_t)NBLK * CHUNK * 4;
  unsigned int* rec_src = (unsigned int*)ws; ws += (size_t)NBLK * CHUNK * 4;
  unsigned int* eix2 = (unsigned int*)ws; ws += (size_t)Ee * 4;
  float2* alpha2 = (float2*)ws;           ws += (size_t)Ee * 8;
  int* off = (int*)ws;                    ws += (size_t)(Nn + 1) * 4;
  int* cnt_tbl = (int*)ws;                ws += (size_t)NBLK * NCB * 4;
  int* base_tbl = (int*)ws;               ws += (size_t)NBLK * NCB * 4;
  int* cnt_tbl2 = (int*)ws;               ws += (size_t)NBLK * NCB * 4;
  int* base_tbl2 = (int*)ws;              ws += (size_t)NBLK * NCB * 4;
  int* segdst = (int*)ws;                 ws += (size_t)NCB * NBLK * 4;
  int* segdst2 = (int*)ws;                ws += (size_t)NCB * NBLK * 4;
  int* coarse_base = (int*)ws;            ws += (size_t)(NCB + 1) * 4;
  int* btot = (int*)ws;                   ws += (size_t)NCB * 4;
  int* btot2 = (int*)ws;                  ws += (size_t)NCB * 4;

  k1_gemm<<<1024, 128, 0, stream>>>(x, W, bW, att, hb, ai, aj, Nn);
  k_bin<<<NBLK, 256, 0, stream>>>(ei, eatt, rec, cnt_tbl, base_tbl, rec_src,
                                  cnt_tbl2, base_tbl2, Ee, NCB);
  k_segoff_a<<<NCB, 256, 0, stream>>>(cnt_tbl, segdst, btot, NCB, NBLK);
  k_segoff_a<<<NCB, 256, 0, stream>>>(cnt_tbl2, segdst2, btot2, NCB, NBLK);
  k_segoff_b<<<1, 512, 0, stream>>>(btot, coarse_base, NCB, Ee);
  k_sacc<<<NCB, 256, 0, stream>>>(rec_src, cnt_tbl2, base_tbl2, segdst2, btot2,
                                  (const float2*)ai, (const float2*)aj, att,
                                  bemb, sden, Nn, NCB, NBLK);
  k_sort<<<NCB, 256, 0, stream>>>(rec, cnt_tbl, base_tbl, segdst, coarse_base,
                                  (const float2*)ai, (const float2*)aj,
                                  (const float2*)sden, att, bemb, eix2, alpha2,
                                  off, Nn, NCB, NBLK, Ee);
  k_gather<<<(Nn + 3) / 4, 256, 0, stream>>>(eix2, alpha2, off, hb, bemb, bias,
                                             (float*)d_out, Nn);
}